// Round 1
// baseline (850.208 us; speedup 1.0000x reference)
//
#include <hip/hip_runtime.h>
#include <hip/hip_bf16.h>

// Problem constants (from setup_inputs)
#define B_N   8
#define C_N   256
#define H_N   64
#define W_N   64
#define G_N   4
#define CG_N  64
#define K_N   9
#define CO_N  256
#define KC_N  2304          // C_N * K_N — GEMM reduction length
#define PIX   8             // pixels (along w) per block
#define NTHR  512
#define SC_N  8             // s-chunks (one per wave)
#define SLEN  (KC_N / SC_N) // 288

// ---------------------------------------------------------------------------
// Kernel 1: transpose w_d [Co][C*9] -> wd_t [C*9][Co] so MAC reads coalesce.
// ---------------------------------------------------------------------------
__global__ void transpose_w_kernel(const float* __restrict__ w_d,
                                   float* __restrict__ wd_t) {
    int o = blockIdx.x;  // 256 blocks
    for (int s = threadIdx.x; s < KC_N; s += blockDim.x)
        wd_t[(size_t)s * CO_N + o] = w_d[(size_t)o * KC_N + s];
}

// ---------------------------------------------------------------------------
// Kernel 2: fused offsets -> bilinear sampling (bf16 in LDS) -> fp32 MAC.
// Block = 512 threads handles (b, h, w0..w0+7) x all 256 output channels.
// MAC tiling: tid = sc*64 + oq; thread owns o in [4*oq,4*oq+4), s-chunk sc.
// ---------------------------------------------------------------------------
__global__ __launch_bounds__(NTHR) void featadapt_kernel(
    const float* __restrict__ x,
    const float* __restrict__ wh_pred,
    const float* __restrict__ w_off,
    const float* __restrict__ b_off,
    const float* __restrict__ b_d,
    const float* __restrict__ wd_t,
    float* __restrict__ out)
{
    extern __shared__ unsigned char lds_raw[];
    __hip_bfloat16* samp = (__hip_bfloat16*)lds_raw;         // PIX*KC_N bf16 = 36864 B
    float* fbase = (float*)(lds_raw + PIX * KC_N * 2);
    float* pypx = fbase;                     // PIX*G_N*K_N*2 = 576 floats
    float* woff = pypx + PIX * G_N * K_N * 2; // 144
    float* boff = woff + 144;                 // 72
    float* whs  = boff + 72;                  // PIX*8 = 64

    const int tid = threadIdx.x;
    const int bid = blockIdx.x;               // B*H*(W/PIX) = 8*64*8 = 4096
    const int b   = bid >> 9;                 // / 512
    const int rem = bid & 511;
    const int h   = rem >> 3;
    const int w0  = (rem & 7) * PIX;

    // ---- stage small tensors ----
    if (tid < 144) {
        woff[tid] = w_off[tid];
    } else if (tid < 216) {
        boff[tid - 144] = b_off[tid - 144];
    } else if (tid < 216 + PIX * 8) {
        int i = tid - 216;
        int p = i >> 3, j = i & 7;            // wh_pred[b, j, h, w0+p]
        whs[i] = wh_pred[(((size_t)b * 8 + j) * H_N + h) * W_N + (w0 + p)];
    }
    __syncthreads();

    // ---- sampling coordinates: off = wh0*w_off[..0] + wh1*w_off[..1] + b_off ----
    for (int i = tid; i < PIX * G_N * K_N; i += NTHR) {   // 288 entries
        int p  = i / (G_N * K_N);
        int gk = i % (G_N * K_N);
        int g = gk / K_N, k = gk % K_N;
        float wh0 = whs[p * 8 + 2 * g];
        float wh1 = whs[p * 8 + 2 * g + 1];
        int oy = 2 * k, ox = 2 * k + 1;
        float offy = wh0 * woff[(g * 18 + oy) * 2 + 0] + wh1 * woff[(g * 18 + oy) * 2 + 1] + boff[g * 18 + oy];
        float offx = wh0 * woff[(g * 18 + ox) * 2 + 0] + wh1 * woff[(g * 18 + ox) * 2 + 1] + boff[g * 18 + ox];
        pypx[i * 2 + 0] = offy + (float)(k / 3 - 1 + h);
        pypx[i * 2 + 1] = offx + (float)(k % 3 - 1 + w0 + p);
    }
    __syncthreads();

    // ---- bilinear sampling into LDS (bf16), layout samp[p][s], s = cf*9 + k ----
    const float* xb = x + (size_t)b * C_N * H_N * W_N;
    for (int u = tid; u < PIX * KC_N; u += NTHR) {
        int p  = u / KC_N;
        int r  = u - p * KC_N;
        int cf = r / K_N;
        int k  = r - cf * K_N;
        int g  = cf >> 6;                      // / CG_N
        int ci = (p * G_N + g) * K_N + k;
        float py = pypx[ci * 2 + 0];
        float px = pypx[ci * 2 + 1];
        float fy = floorf(py), fx = floorf(px);
        int y0 = (int)fy, x0 = (int)fx;
        float wy = py - fy, wx = px - fx;
        int y1 = y0 + 1, x1 = x0 + 1;
        const float* xc = xb + (size_t)cf * (H_N * W_N);
        float v00 = (y0 >= 0 && y0 < H_N && x0 >= 0 && x0 < W_N) ? xc[y0 * W_N + x0] : 0.f;
        float v01 = (y0 >= 0 && y0 < H_N && x1 >= 0 && x1 < W_N) ? xc[y0 * W_N + x1] : 0.f;
        float v10 = (y1 >= 0 && y1 < H_N && x0 >= 0 && x0 < W_N) ? xc[y1 * W_N + x0] : 0.f;
        float v11 = (y1 >= 0 && y1 < H_N && x1 >= 0 && x1 < W_N) ? xc[y1 * W_N + x1] : 0.f;
        float val = v00 * (1.f - wy) * (1.f - wx) + v01 * (1.f - wy) * wx
                  + v10 * wy * (1.f - wx)        + v11 * wy * wx;
        samp[u] = __float2bfloat16(val);
    }
    __syncthreads();

    // ---- MAC: acc[p][j] += samp[p][s] * wd_t[s][4*oq+j] ----
    const int oq = tid & 63;
    const int sc = tid >> 6;        // wave-uniform -> samp reads are broadcasts
    float acc[PIX][4];
    #pragma unroll
    for (int p = 0; p < PIX; ++p) {
        acc[p][0] = 0.f; acc[p][1] = 0.f; acc[p][2] = 0.f; acc[p][3] = 0.f;
    }
    const float4* wt = (const float4*)wd_t;
    const int s_begin = sc * SLEN;
    for (int s = s_begin; s < s_begin + SLEN; ++s) {
        float4 w4 = wt[(size_t)s * 64 + oq];   // 1 KB contiguous per wave, L2-hit
        #pragma unroll
        for (int p = 0; p < PIX; ++p) {
            float f = __bfloat162float(samp[p * KC_N + s]);
            acc[p][0] += f * w4.x;
            acc[p][1] += f * w4.y;
            acc[p][2] += f * w4.z;
            acc[p][3] += f * w4.w;
        }
    }
    __syncthreads();   // everyone done reading samp; reuse its LDS for reduction

    // ---- reduction over sc (two passes of 4 pixels), then store ----
    float*  redf = (float*)lds_raw;            // 8*4*256 floats = 32 KB per pass
    float4* red4 = (float4*)lds_raw;
    const int o_w = tid & 255;
    const int pq  = tid >> 8;                   // 0..1
    const size_t out_base = (((size_t)b * CO_N + o_w) * H_N + h) * W_N;

    // pass 0: pixels 0..3
    #pragma unroll
    for (int pp = 0; pp < 4; ++pp)
        red4[(sc * 4 + pp) * 64 + oq] = make_float4(acc[pp][0], acc[pp][1], acc[pp][2], acc[pp][3]);
    __syncthreads();
    {
        float bd = b_d[o_w];
        float r0 = bd, r1 = bd;
        #pragma unroll
        for (int s2 = 0; s2 < SC_N; ++s2) {
            r0 += redf[(s2 * 4 + pq * 2 + 0) * 256 + o_w];
            r1 += redf[(s2 * 4 + pq * 2 + 1) * 256 + o_w];
        }
        *(float2*)&out[out_base + w0 + pq * 2] = make_float2(r0, r1);
    }
    __syncthreads();

    // pass 1: pixels 4..7
    #pragma unroll
    for (int pp = 0; pp < 4; ++pp)
        red4[(sc * 4 + pp) * 64 + oq] = make_float4(acc[4 + pp][0], acc[4 + pp][1], acc[4 + pp][2], acc[4 + pp][3]);
    __syncthreads();
    {
        float bd = b_d[o_w];
        float r0 = bd, r1 = bd;
        #pragma unroll
        for (int s2 = 0; s2 < SC_N; ++s2) {
            r0 += redf[(s2 * 4 + pq * 2 + 0) * 256 + o_w];
            r1 += redf[(s2 * 4 + pq * 2 + 1) * 256 + o_w];
        }
        *(float2*)&out[out_base + w0 + 4 + pq * 2] = make_float2(r0, r1);
    }
}

// ---------------------------------------------------------------------------
extern "C" void kernel_launch(void* const* d_in, const int* in_sizes, int n_in,
                              void* d_out, int out_size, void* d_ws, size_t ws_size,
                              hipStream_t stream) {
    const float* x     = (const float*)d_in[0];
    const float* whp   = (const float*)d_in[1];
    const float* w_off = (const float*)d_in[2];
    const float* b_off = (const float*)d_in[3];
    const float* w_d   = (const float*)d_in[4];
    const float* b_d   = (const float*)d_in[5];
    float* out  = (float*)d_out;
    float* wd_t = (float*)d_ws;   // 2304*256*4 = 2.36 MB scratch

    hipLaunchKernelGGL(transpose_w_kernel, dim3(CO_N), dim3(256), 0, stream, w_d, wd_t);

    size_t lds_bytes = (size_t)PIX * KC_N * 2
                     + (size_t)(PIX * G_N * K_N * 2 + 144 + 72 + PIX * 8) * sizeof(float);
    hipLaunchKernelGGL(featadapt_kernel,
                       dim3(B_N * H_N * (W_N / PIX)), dim3(NTHR), lds_bytes, stream,
                       x, whp, w_off, b_off, b_d, wd_t, out);
}

// Round 2
// 381.472 us; speedup vs baseline: 2.2288x; 2.2288x over previous
//
#include <hip/hip_runtime.h>

typedef __attribute__((ext_vector_type(8))) short bh8;
typedef __attribute__((ext_vector_type(4))) float f4;

#define NTHR 512

// float -> bf16 round-nearest-even (finite inputs)
__device__ __forceinline__ unsigned short f2bf(float f) {
    unsigned int u = __builtin_bit_cast(unsigned int, f);
    u += 0x7FFFu + ((u >> 16) & 1u);
    return (unsigned short)(u >> 16);
}

// ---------------------------------------------------------------------------
// Pack w_d [Co=256][K=2304] f32 -> bf16 MFMA B-fragments:
// bpack[(t*16+nb)*64 + l][e] = bf16(w_d[nb*16+(l&15)][t*32 + (l>>4)*8 + e])
// so a wave's B-fragment load is lane-contiguous 16B (global_load_dwordx4).
// ---------------------------------------------------------------------------
__global__ __launch_bounds__(256) void pack_w_kernel(const float* __restrict__ w_d,
                                                     bh8* __restrict__ bp) {
    int idx = blockIdx.x * 256 + threadIdx.x;   // 72*16*64 = 73728 threads
    int l = idx & 63;
    int nbt = idx >> 6;                          // t*16 + nb
    int o  = (nbt & 15) * 16 + (l & 15);
    int k0 = (nbt >> 4) * 32 + (l >> 4) * 8;
    const float* s = w_d + (size_t)o * 2304 + k0;
    bh8 v;
    #pragma unroll
    for (int e = 0; e < 8; ++e) v[e] = (short)f2bf(s[e]);
    bp[idx] = v;
}

// ---------------------------------------------------------------------------
// Fused: offsets -> bilinear sample (bf16, swizzled LDS) -> MFMA implicit GEMM.
// Block = (b, h) row: 64 pixels x 256 outputs. 8 waves.
// K = 2304 in 8 chunks of 32 channels (288 K-elems, 9 MFMA t-steps each).
// ---------------------------------------------------------------------------
__global__ __launch_bounds__(NTHR) void featadapt_mfma(
    const float* __restrict__ x,
    const float* __restrict__ wh_pred,
    const float* __restrict__ w_off,
    const float* __restrict__ b_off,
    const float* __restrict__ b_d,
    const bh8* __restrict__ bp,
    float* __restrict__ out)
{
    extern __shared__ unsigned char lds[];
    unsigned char* samp = lds;                       // 64 rows * 576 B = 36864
    float2* pyx = (float2*)(lds + 36864);            // 64*36 float2 = 18432
    float*  whs = (float*)(lds + 55296);             // 64*8 = 2048 B
    float*  woff = (float*)(lds + 57344);            // 144 f
    float*  boff = (float*)(lds + 57920);            // 72 f

    const int tid = threadIdx.x;
    const int b = blockIdx.x >> 6;
    const int h = blockIdx.x & 63;

    // stage wh_pred row + small params
    {
        int j = tid >> 6, w = tid & 63;
        whs[w * 8 + j] = wh_pred[(((size_t)b * 8 + j) * 64 + h) * 64 + w];
    }
    if (tid < 144) woff[tid] = w_off[tid];
    else if (tid < 216) boff[tid - 144] = b_off[tid - 144];
    __syncthreads();

    // sampling coords: i = p*36 + g*9 + k  (p = pixel = w coordinate)
    for (int i = tid; i < 2304; i += NTHR) {
        int p = i / 36;
        int r = i - p * 36;
        int g = r / 9;
        int k = r - g * 9;
        float wh0 = whs[p * 8 + 2 * g], wh1 = whs[p * 8 + 2 * g + 1];
        int oy = 2 * k, ox = 2 * k + 1;
        float offy = wh0 * woff[(g * 18 + oy) * 2] + wh1 * woff[(g * 18 + oy) * 2 + 1] + boff[g * 18 + oy];
        float offx = wh0 * woff[(g * 18 + ox) * 2] + wh1 * woff[(g * 18 + ox) * 2 + 1] + boff[g * 18 + ox];
        int ky = k / 3;
        pyx[i] = make_float2(offy + (float)(ky - 1 + h),
                             offx + (float)(k - ky * 3 - 1 + p));
    }

    const int l    = tid & 63;
    const int wv   = tid >> 6;
    const int mb0  = (wv >> 2) * 2;     // 0 or 2: wave's M-frag pair base
    const int nbb  = (wv & 3) * 4;      // wave's N-frag base (4 frags)
    const int lrow = l & 15;
    const int lk   = l >> 4;

    f4 acc[2][4];
    #pragma unroll
    for (int i2 = 0; i2 < 2; ++i2)
        #pragma unroll
        for (int n = 0; n < 4; ++n)
            acc[i2][n] = (f4){0.f, 0.f, 0.f, 0.f};

    for (int cc = 0; cc < 8; ++cc) {
        const int g = cc >> 1;                        // channel group (64 ch/group)
        const float* xb = x + ((size_t)b * 256 + cc * 32) * 4096;
        __syncthreads();    // previous chunk's MFMA done reading samp

        // sample 64 pix * 32 ch * 9 taps; thread = (p, k, 4-channel quad)
        for (int u = tid; u < 4608; u += NTHR) {
            int p  = u / 72;
            int r  = u - p * 72;
            int k  = r >> 3;
            int c0 = (r & 7) * 4;
            float2 cp = pyx[p * 36 + g * 9 + k];
            float fy = floorf(cp.x), fx = floorf(cp.y);
            int y0 = (int)fy, x0 = (int)fx;
            float wy = cp.x - fy, wx = cp.y - fx;
            int y0c = min(max(y0, 0), 63), y1c = min(max(y0 + 1, 0), 63);
            int x0c = min(max(x0, 0), 63), x1c = min(max(x0 + 1, 0), 63);
            float my0 = (y0 >= 0 && y0 < 64) ? 1.f : 0.f;
            float my1 = (y0 >= -1 && y0 < 63) ? 1.f : 0.f;
            float mx0 = (x0 >= 0 && x0 < 64) ? 1.f : 0.f;
            float mx1 = (x0 >= -1 && x0 < 63) ? 1.f : 0.f;
            float w00 = (1.f - wy) * (1.f - wx) * my0 * mx0;
            float w01 = (1.f - wy) * wx * my0 * mx1;
            float w10 = wy * (1.f - wx) * my1 * mx0;
            float w11 = wy * wx * my1 * mx1;
            int a00 = y0c * 64 + x0c, a01 = y0c * 64 + x1c;
            int a10 = y1c * 64 + x0c, a11 = y1c * 64 + x1c;
            const float* xc = xb + (size_t)c0 * 4096;
            int sb = c0 * 9 + k;
            #pragma unroll
            for (int ci = 0; ci < 4; ++ci) {
                float v = xc[a00] * w00 + xc[a01] * w01 + xc[a10] * w10 + xc[a11] * w11;
                int byte = p * 576 + (sb + ci * 9) * 2;
                byte ^= (p & 7) << 4;                 // XOR swizzle (write side)
                *(unsigned short*)(samp + byte) = f2bf(v);
                xc += 4096;
            }
        }
        __syncthreads();

        // MFMA: 9 t-steps over this chunk's 288 K-elems
        #pragma unroll 3
        for (int tt = 0; tt < 9; ++tt) {
            int row0 = mb0 * 16 + lrow;
            int row1 = row0 + 16;
            int byt0 = (row0 * 576 + tt * 64 + lk * 16) ^ ((row0 & 7) << 4);
            int byt1 = (row1 * 576 + tt * 64 + lk * 16) ^ ((row1 & 7) << 4);
            bh8 a0 = *(const bh8*)(samp + byt0);
            bh8 a1 = *(const bh8*)(samp + byt1);
            int tg = cc * 9 + tt;
            #pragma unroll
            for (int n = 0; n < 4; ++n) {
                bh8 bf = bp[((size_t)tg * 16 + nbb + n) * 64 + l];
                acc[0][n] = __builtin_amdgcn_mfma_f32_16x16x32_bf16(a0, bf, acc[0][n], 0, 0, 0);
                acc[1][n] = __builtin_amdgcn_mfma_f32_16x16x32_bf16(a1, bf, acc[1][n], 0, 0, 0);
            }
        }
    }

    // epilogue: D row = pixel w = mb*16 + lk*4 + reg -> one float4 store per frag
    const int wbase0 = mb0 * 16 + lk * 4;
    #pragma unroll
    for (int n = 0; n < 4; ++n) {
        int o = (nbb + n) * 16 + lrow;
        float bd = b_d[o];
        size_t ob = (((size_t)b * 256 + o) * 64 + h) * 64;
        #pragma unroll
        for (int im = 0; im < 2; ++im) {
            f4 v = acc[im][n];
            float4 s4 = make_float4(v[0] + bd, v[1] + bd, v[2] + bd, v[3] + bd);
            *(float4*)&out[ob + wbase0 + im * 16] = s4;
        }
    }
}

// ---------------------------------------------------------------------------
extern "C" void kernel_launch(void* const* d_in, const int* in_sizes, int n_in,
                              void* d_out, int out_size, void* d_ws, size_t ws_size,
                              hipStream_t stream) {
    const float* x     = (const float*)d_in[0];
    const float* whp   = (const float*)d_in[1];
    const float* w_off = (const float*)d_in[2];
    const float* b_off = (const float*)d_in[3];
    const float* w_d   = (const float*)d_in[4];
    const float* b_d   = (const float*)d_in[5];
    float* out = (float*)d_out;
    bh8* bpack = (bh8*)d_ws;     // 73728 * 16 B = 1.18 MB scratch

    hipLaunchKernelGGL(pack_w_kernel, dim3(288), dim3(256), 0, stream, w_d, bpack);
    hipLaunchKernelGGL(featadapt_mfma, dim3(512), dim3(NTHR), 58208, stream,
                       x, whp, w_off, b_off, b_d, bpack, out);
}

// Round 3
// 118.177 us; speedup vs baseline: 7.1943x; 3.2280x over previous
//
#include <hip/hip_runtime.h>

typedef __attribute__((ext_vector_type(8))) short bh8;
typedef __attribute__((ext_vector_type(4))) float f4;

#define NTHR 512

__device__ __forceinline__ unsigned short f2bf(float f) {
    unsigned int u = __builtin_bit_cast(unsigned int, f);
    u += 0x7FFFu + ((u >> 16) & 1u);
    return (unsigned short)(u >> 16);
}
__device__ __forceinline__ float bf2f(unsigned short s) {
    return __builtin_bit_cast(float, ((unsigned int)s) << 16);
}

// ---------------------------------------------------------------------------
// Kernel 1: x [B][C][H][W] f32 -> xt [B][H][W][C] bf16 (channel-last).
// Block = (b, h, cq of 64 channels). LDS 64x65 f32 tile, coalesced both sides.
// ---------------------------------------------------------------------------
__global__ __launch_bounds__(256) void transpose_x_kernel(
    const float* __restrict__ x, unsigned short* __restrict__ xt) {
    __shared__ float tile[64 * 65];
    const int bid = blockIdx.x;            // 8*64*4 = 2048
    const int cq = bid & 3;
    const int h  = (bid >> 2) & 63;
    const int b  = bid >> 8;
    const int tid = threadIdx.x;
    const int w = tid & 63, ci = tid >> 6;
    #pragma unroll
    for (int c0 = 0; c0 < 64; c0 += 4)
        tile[(c0 + ci) * 65 + w] =
            x[(((size_t)b * 256 + cq * 64 + c0 + ci) * 64 + h) * 64 + w];
    __syncthreads();
    const int c2 = tid & 63, w2q = tid >> 6;
    #pragma unroll
    for (int w0 = 0; w0 < 64; w0 += 4) {
        int ww = w0 + w2q;
        xt[(((size_t)b * 64 + h) * 64 + ww) * 256 + cq * 64 + c2] =
            f2bf(tile[c2 * 65 + ww]);
    }
}

// ---------------------------------------------------------------------------
// Kernel 2: pack w_d [256][2304] f32 -> bf16 B-fragments, K reordered k-major.
// bp[((cc*9+tt)*16+nb)*64+l][e] = bf16(w_d[nb*16+(l&15)][(cc*32+(l>>4)*8+e)*9+tt])
// Block = (cc, nb): stage 16 rows x 288 contiguous floats in LDS, emit coalesced.
// ---------------------------------------------------------------------------
__global__ __launch_bounds__(256) void pack_w_kernel(const float* __restrict__ w_d,
                                                     bh8* __restrict__ bp) {
    __shared__ float ldw[16 * 289];
    const int cc = blockIdx.x >> 4;
    const int nb = blockIdx.x & 15;
    const int tid = threadIdx.x;
    for (int i = tid; i < 16 * 288; i += 256) {
        int oi = i / 288, j = i - oi * 288;
        ldw[oi * 289 + j] = w_d[((size_t)(nb * 16 + oi)) * 2304 + cc * 288 + j];
    }
    __syncthreads();
    for (int u = tid; u < 576; u += 256) {
        int tt = u >> 6, l = u & 63;
        int lrow = l & 15, lk = l >> 4;
        bh8 v;
        #pragma unroll
        for (int e = 0; e < 8; ++e)
            v[e] = (short)f2bf(ldw[lrow * 289 + (lk * 8 + e) * 9 + tt]);
        bp[((size_t)(cc * 9 + tt) * 16 + nb) * 64 + l] = v;
    }
}

// ---------------------------------------------------------------------------
// Kernel 3: fused offsets -> bilinear sample (bf16 LDS, k-major) -> MFMA.
// Block = (b, h, mh): 32 pixels x 256 outputs, 8 waves, 4 blocks/CU.
// ---------------------------------------------------------------------------
__global__ __launch_bounds__(NTHR, 8) void featadapt_mfma(
    const unsigned short* __restrict__ xt,
    const float* __restrict__ wh_pred,
    const float* __restrict__ w_off,
    const float* __restrict__ b_off,
    const float* __restrict__ b_d,
    const bh8* __restrict__ bp,
    float* __restrict__ out)
{
    extern __shared__ unsigned char lds[];
    unsigned char* samp = lds;                      // 32 * 576 B = 18432
    float* whs  = (float*)(lds + 18432);            // 32*8 = 256 f
    float* woff = (float*)(lds + 19456);            // 144 f
    float* boff = (float*)(lds + 20032);            // 72 f

    const int tid = threadIdx.x;
    const int bid = blockIdx.x;                     // 8*64*2 = 1024
    const int mh = bid & 1;
    const int h  = (bid >> 1) & 63;
    const int b  = bid >> 7;

    if (tid < 256) {
        int j = tid >> 5, p = tid & 31;             // lanes p-fast: coalesced
        whs[p * 8 + j] = wh_pred[(((size_t)b * 8 + j) * 64 + h) * 64 + mh * 32 + p];
    } else if (tid < 256 + 144) {
        woff[tid - 256] = w_off[tid - 256];
    } else if (tid < 256 + 216) {
        boff[tid - 400] = b_off[tid - 400];
    }

    const int l    = tid & 63;
    const int wv   = tid >> 6;
    const int im   = wv >> 2;       // M-frag (0..1)
    const int nq   = wv & 3;        // N-quad: frags nq*4..nq*4+3
    const int lrow = l & 15;
    const int lk   = l >> 4;

    f4 acc[4];
    #pragma unroll
    for (int n = 0; n < 4; ++n) acc[n] = (f4){0.f, 0.f, 0.f, 0.f};

    __syncthreads();

    for (int cc = 0; cc < 8; ++cc) {
        const int g = cc >> 1;
        // ---- sample: 32 pix * 9 taps * 4 octets(8ch) = 1152 items ----
        for (int u = tid; u < 1152; u += NTHR) {
            int p = u / 36;
            int r = u - p * 36;
            int k = r >> 2;
            int oct = r & 3;
            float wh0 = whs[p * 8 + 2 * g], wh1 = whs[p * 8 + 2 * g + 1];
            int oy = 2 * k, ox = 2 * k + 1;
            float offy = wh0 * woff[(g * 18 + oy) * 2] + wh1 * woff[(g * 18 + oy) * 2 + 1] + boff[g * 18 + oy];
            float offx = wh0 * woff[(g * 18 + ox) * 2] + wh1 * woff[(g * 18 + ox) * 2 + 1] + boff[g * 18 + ox];
            int ky = k / 3;
            float py = offy + (float)(ky - 1 + h);
            float px = offx + (float)(k - ky * 3 - 1 + mh * 32 + p);
            float fy = floorf(py), fx = floorf(px);
            int y0 = (int)fy, x0 = (int)fx;
            float wy = py - fy, wx = px - fx;
            int y0c = min(max(y0, 0), 63), y1c = min(max(y0 + 1, 0), 63);
            int x0c = min(max(x0, 0), 63), x1c = min(max(x0 + 1, 0), 63);
            float my0 = (y0 >= 0 && y0 < 64) ? 1.f : 0.f;
            float my1 = (y0 >= -1 && y0 < 63) ? 1.f : 0.f;
            float mx0 = (x0 >= 0 && x0 < 64) ? 1.f : 0.f;
            float mx1 = (x0 >= -1 && x0 < 63) ? 1.f : 0.f;
            float w00 = (1.f - wy) * (1.f - wx) * my0 * mx0;
            float w01 = (1.f - wy) * wx * my0 * mx1;
            float w10 = wy * (1.f - wx) * my1 * mx0;
            float w11 = wy * wx * my1 * mx1;
            const int cb = cc * 32 + oct * 8;
            const unsigned short* xb = xt + (size_t)b * (64 * 64 * 256) + cb;
            bh8 t00 = *(const bh8*)(xb + (y0c * 64 + x0c) * 256);
            bh8 t01 = *(const bh8*)(xb + (y0c * 64 + x1c) * 256);
            bh8 t10 = *(const bh8*)(xb + (y1c * 64 + x0c) * 256);
            bh8 t11 = *(const bh8*)(xb + (y1c * 64 + x1c) * 256);
            bh8 o8;
            #pragma unroll
            for (int j = 0; j < 8; ++j) {
                float v = w00 * bf2f((unsigned short)t00[j])
                        + w01 * bf2f((unsigned short)t01[j])
                        + w10 * bf2f((unsigned short)t10[j])
                        + w11 * bf2f((unsigned short)t11[j]);
                o8[j] = (short)f2bf(v);
            }
            int byt = (p * 576 + k * 64 + oct * 16) ^ ((p & 7) << 4);
            *(bh8*)(samp + byt) = o8;
        }
        __syncthreads();

        // ---- MFMA: 9 t-steps ----
        #pragma unroll 3
        for (int tt = 0; tt < 9; ++tt) {
            int row = im * 16 + lrow;
            int byt = (row * 576 + tt * 64 + lk * 16) ^ ((row & 7) << 4);
            bh8 a = *(const bh8*)(samp + byt);
            int tg = cc * 9 + tt;
            #pragma unroll
            for (int n = 0; n < 4; ++n) {
                bh8 bw = bp[((size_t)tg * 16 + nq * 4 + n) * 64 + l];
                acc[n] = __builtin_amdgcn_mfma_f32_16x16x32_bf16(a, bw, acc[n], 0, 0, 0);
            }
        }
        __syncthreads();
    }

    // ---- epilogue ----
    const int wbase = mh * 32 + im * 16 + lk * 4;
    #pragma unroll
    for (int n = 0; n < 4; ++n) {
        int o = (nq * 4 + n) * 16 + lrow;
        float bd = b_d[o];
        f4 v = acc[n];
        float4 s4 = make_float4(v[0] + bd, v[1] + bd, v[2] + bd, v[3] + bd);
        *(float4*)&out[(((size_t)b * 256 + o) * 64 + h) * 64 + wbase] = s4;
    }
}

// ---------------------------------------------------------------------------
extern "C" void kernel_launch(void* const* d_in, const int* in_sizes, int n_in,
                              void* d_out, int out_size, void* d_ws, size_t ws_size,
                              hipStream_t stream) {
    const float* x     = (const float*)d_in[0];
    const float* whp   = (const float*)d_in[1];
    const float* w_off = (const float*)d_in[2];
    const float* b_off = (const float*)d_in[3];
    const float* w_d   = (const float*)d_in[4];
    const float* b_d   = (const float*)d_in[5];
    float* out = (float*)d_out;

    unsigned short* xt = (unsigned short*)d_ws;                  // 16.78 MB
    bh8* bp = (bh8*)((char*)d_ws + (size_t)8 * 64 * 64 * 256 * 2); // +1.18 MB

    hipLaunchKernelGGL(transpose_x_kernel, dim3(2048), dim3(256), 0, stream, x, xt);
    hipLaunchKernelGGL(pack_w_kernel, dim3(128), dim3(256), 0, stream, w_d, bp);
    hipLaunchKernelGGL(featadapt_mfma, dim3(1024), dim3(NTHR), 20320, stream,
                       xt, whp, w_off, b_off, b_d, bp, out);
}